// Round 15
// baseline (264.171 us; speedup 1.0000x reference)
//
#include <hip/hip_runtime.h>
#include <hip/hip_fp16.h>
#include <math.h>

#define BB 16
#define NN 96
#define NE 256
#define FF (BB*NN)      // 1536
#define ATOM 128
#define EDIM 16
#define HID 128
#define LAT 128
#define RBFN 16
#define CUTOFF 5.0f
#define ZEMB 32
#define E_ATT 1024
#define M0I 64
#define M1I 32
#define M0O 32
#define M1O 16
#define NODE_DIM 160
#define OUT_DIM 80
#define INVD 48
#define WNUM 4608
#define SEG1 2048
#define SEG2 3072
#define SEG3 3584

#define EDGE_BLKS (E_ATT/4)  // 256
#define EC_BLKS 16
#define HABS_BLKS 2
#define GATE_BLKS 16
#define TRANS_BLKS 144
#define PREP_BLKS 1
#define STAGE1_BLKS (EDGE_BLKS + EC_BLKS + HABS_BLKS + GATE_BLKS + TRANS_BLKS + PREP_BLKS)  // 435

#define MFMA_BLKS (36*16)  // 576
#define MQ_BLKS (MFMA_BLKS + 512)

#define SCORE_BLKS 128
#define ST_BLKS (SCORE_BLKS + 512)

typedef _Float16 half8_t __attribute__((ext_vector_type(8)));
typedef float float4v __attribute__((ext_vector_type(4)));

__device__ __forceinline__ float silu_f(float x) { return x / (1.0f + expf(-x)); }

// ---------------- stage1 mega-kernel (unchanged from R14) ----------------
__global__ __launch_bounds__(256) void k_stage1(
    const float* __restrict__ h, const float* __restrict__ z_emb, const int* __restrict__ z,
    const int* __restrict__ absorber, const float* __restrict__ e_feat,
    const int* __restrict__ att_dst, const float* __restrict__ att_dist,
    const float* __restrict__ att_vec,
    const float* __restrict__ rw1, const float* __restrict__ rb1,
    const float* __restrict__ kw1, const float* __restrict__ kb1,
    const float* __restrict__ kw2, const float* __restrict__ kb2,
    const float* __restrict__ kw3, const float* __restrict__ kb3,
    const float* __restrict__ qw1,
    const float* __restrict__ ew1, const float* __restrict__ eb1,
    const float* __restrict__ ew2, const float* __restrict__ eb2,
    const float* __restrict__ rw2,
    __half* __restrict__ hiddenH, float* __restrict__ kmatw,
    float* __restrict__ ecw, float* __restrict__ habs1w, float* __restrict__ gexp,
    __half* __restrict__ rw2T,
    int* __restrict__ inv, float* __restrict__ y1E, float* __restrict__ envE)
{
    __shared__ float smem[3488];
    int blk = blockIdx.x;
    int t = threadIdx.x;

    if (blk < EDGE_BLKS) {
        float (*sin1)[184] = (float(*)[184])smem;
        float (*l1S)[128]  = (float(*)[128])(smem + 736);
        float (*l2S)[128]  = (float(*)[128])(smem + 736 + 512);
        int w = t >> 6;
        int c = t & 63;
        int e = blk*4 + w;
        int f = att_dst[e];
        int b = f / NN, nn = f - b*NN;
        float d = att_dist[e];
        {
            float2 hv = *(const float2*)&h[f*ATOM + 2*c];
            sin1[w][2*c] = hv.x; sin1[w][2*c + 1] = hv.y;
        }
        if (c < ZEMB) sin1[w][ATOM + c] = z_emb[z[f]*ZEMB + c];
        if (c >= 32 && c < 48) {
            int j = c - 32;
            const float delta = CUTOFF / (RBFN - 1);
            float diff = d - j*delta;
            sin1[w][ATOM + ZEMB + 1 + j] = expf(-diff*diff / (2.0f*delta*delta));
        }
        if (c == 48) sin1[w][ATOM + ZEMB] = (absorber[b] == nn) ? 1.0f : 0.0f;
        __syncthreads();
        int c2 = 2*c;
        {
            float2 a0 = *(const float2*)&rb1[c2];
            float2 a1 = make_float2(0.f, 0.f);
            #pragma unroll 8
            for (int i = 0; i < 48; i += 2) {
                float x0v = sin1[w][ATOM + i], x1v = sin1[w][ATOM + i + 1];
                float2 w0 = *(const float2*)&rw1[i*HID + c2];
                float2 w1 = *(const float2*)&rw1[(i+1)*HID + c2];
                a0.x += x0v*w0.x; a0.y += x0v*w0.y;
                a1.x += x1v*w1.x; a1.y += x1v*w1.y;
            }
            {
                float x0v = sin1[w][ATOM + 48];
                float2 w0 = *(const float2*)&rw1[48*HID + c2];
                a0.x += x0v*w0.x; a0.y += x0v*w0.y;
            }
            *(__half2*)&hiddenH[e*HID + c2] =
                __floats2half2_rn(silu_f(a0.x + a1.x), silu_f(a0.y + a1.y));
        }
        {
            float2 a0 = *(const float2*)&kb1[c2];
            float2 a1 = make_float2(0.f, 0.f);
            #pragma unroll 8
            for (int i = 0; i < 176; i += 2) {
                float x0v = sin1[w][i], x1v = sin1[w][i + 1];
                float2 w0 = *(const float2*)&kw1[i*HID + c2];
                float2 w1 = *(const float2*)&kw1[(i+1)*HID + c2];
                a0.x += x0v*w0.x; a0.y += x0v*w0.y;
                a1.x += x1v*w1.x; a1.y += x1v*w1.y;
            }
            {
                float x0v = sin1[w][176];
                float2 w0 = *(const float2*)&kw1[176*HID + c2];
                a0.x += x0v*w0.x; a0.y += x0v*w0.y;
            }
            l1S[w][c2] = silu_f(a0.x + a1.x); l1S[w][c2+1] = silu_f(a0.y + a1.y);
        }
        __syncthreads();
        {
            float2 a0 = *(const float2*)&kb2[c2];
            float2 a1 = make_float2(0.f, 0.f);
            #pragma unroll 8
            for (int i = 0; i < HID; i += 2) {
                float x0v = l1S[w][i], x1v = l1S[w][i + 1];
                float2 w0 = *(const float2*)&kw2[i*HID + c2];
                float2 w1 = *(const float2*)&kw2[(i+1)*HID + c2];
                a0.x += x0v*w0.x; a0.y += x0v*w0.y;
                a1.x += x1v*w1.x; a1.y += x1v*w1.y;
            }
            l2S[w][c2] = silu_f(a0.x + a1.x); l2S[w][c2+1] = silu_f(a0.y + a1.y);
        }
        __syncthreads();
        {
            float2 a0 = *(const float2*)&kb3[c2];
            float2 a1 = make_float2(0.f, 0.f);
            #pragma unroll 8
            for (int i = 0; i < HID; i += 2) {
                float x0v = l2S[w][i], x1v = l2S[w][i + 1];
                float2 w0 = *(const float2*)&kw3[i*HID + c2];
                float2 w1 = *(const float2*)&kw3[(i+1)*HID + c2];
                a0.x += x0v*w0.x; a0.y += x0v*w0.y;
                a1.x += x1v*w1.x; a1.y += x1v*w1.y;
            }
            float2 o; o.x = a0.x + a1.x; o.y = a0.y + a1.y;
            *(float2*)&kmatw[f*HID + c2] = o;
        }
    } else if (blk < EDGE_BLKS + EC_BLKS) {
        float (*ef)[16] = (float(*)[16])smem;
        int e0 = (blk - EDGE_BLKS) * 16;
        { int e = t >> 4, i = t & 15; ef[e][i] = e_feat[(e0 + e)*EDIM + i]; }
        __syncthreads();
        int r = t >> 4, c0 = (t & 15)*8;
        float4 a0 = make_float4(0,0,0,0), a1 = a0;
        #pragma unroll
        for (int i = 0; i < EDIM; i++) {
            float a = ef[r][i];
            float4 w0 = *(const float4*)&qw1[(ATOM + i)*HID + c0];
            float4 w1 = *(const float4*)&qw1[(ATOM + i)*HID + c0 + 4];
            a0.x += a*w0.x; a0.y += a*w0.y; a0.z += a*w0.z; a0.w += a*w0.w;
            a1.x += a*w1.x; a1.y += a*w1.y; a1.z += a*w1.z; a1.w += a*w1.w;
        }
        *(float4*)&ecw[(e0 + r)*HID + c0] = a0;
        *(float4*)&ecw[(e0 + r)*HID + c0 + 4] = a1;
    } else if (blk < EDGE_BLKS + EC_BLKS + HABS_BLKS) {
        float (*hr)[128] = (float(*)[128])smem;
        int b0 = (blk - EDGE_BLKS - EC_BLKS) * 8;
        {
            int r = t >> 5, i4 = t & 31;
            int b = b0 + r;
            int a = absorber[b];
            *(float4*)&hr[r][i4*4] = *(const float4*)&h[(b*NN + a)*ATOM + i4*4];
        }
        __syncthreads();
        int r = t >> 5, c0 = (t & 31)*4;
        float4 a0 = make_float4(0,0,0,0), a1 = a0;
        #pragma unroll 8
        for (int i = 0; i < ATOM; i += 2) {
            float x0v = hr[r][i], x1v = hr[r][i+1];
            float4 w0 = *(const float4*)&qw1[i*HID + c0];
            float4 w1 = *(const float4*)&qw1[(i+1)*HID + c0];
            a0.x += x0v*w0.x; a0.y += x0v*w0.y; a0.z += x0v*w0.z; a0.w += x0v*w0.w;
            a1.x += x1v*w1.x; a1.y += x1v*w1.y; a1.z += x1v*w1.z; a1.w += x1v*w1.w;
        }
        float4 o;
        o.x = a0.x + a1.x; o.y = a0.y + a1.y; o.z = a0.z + a1.z; o.w = a0.w + a1.w;
        *(float4*)&habs1w[(b0 + r)*HID + c0] = o;
    } else if (blk < EDGE_BLKS + EC_BLKS + HABS_BLKS + GATE_BLKS) {
        float (*ef)[16]   = (float(*)[16])smem;
        float (*l1g)[128] = (float(*)[128])(smem + 256);
        float (*gg)[48]   = (float(*)[48])(smem + 256 + 2048);
        int e0 = (blk - EDGE_BLKS - EC_BLKS - HABS_BLKS) * 16;
        { int e = t >> 4, i = t & 15; ef[e][i] = e_feat[(e0 + e)*EDIM + i]; }
        __syncthreads();
        int r = t >> 4, c0 = (t & 15)*8;
        {
            float4 a0 = *(const float4*)&eb1[c0];
            float4 a1 = *(const float4*)&eb1[c0 + 4];
            #pragma unroll
            for (int i = 0; i < EDIM; i++) {
                float a = ef[r][i];
                float4 w0 = *(const float4*)&ew1[i*HID + c0];
                float4 w1 = *(const float4*)&ew1[i*HID + c0 + 4];
                a0.x += a*w0.x; a0.y += a*w0.y; a0.z += a*w0.z; a0.w += a*w0.w;
                a1.x += a*w1.x; a1.y += a*w1.y; a1.z += a*w1.z; a1.w += a*w1.w;
            }
            l1g[r][c0]   = silu_f(a0.x); l1g[r][c0+1] = silu_f(a0.y);
            l1g[r][c0+2] = silu_f(a0.z); l1g[r][c0+3] = silu_f(a0.w);
            l1g[r][c0+4] = silu_f(a1.x); l1g[r][c0+5] = silu_f(a1.y);
            l1g[r][c0+6] = silu_f(a1.z); l1g[r][c0+7] = silu_f(a1.w);
        }
        __syncthreads();
        for (int u = t; u < 16*48; u += 256) {
            int e = u / 48, j = u - 48*(u/48);
            float acc = eb2[j];
            #pragma unroll 4
            for (int i = 0; i < HID; i++) acc += l1g[e][i]*ew2[i*48 + j];
            gg[e][j] = acc;
        }
        __syncthreads();
        for (int u = t; u < 16*80; u += 256) {
            int e = u / 80, cc = u - 80*(u/80);
            gexp[(e0 + e)*OUT_DIM + cc] = (cc < M0O) ? gg[e][cc] : gg[e][M0O + (cc - M0O)/3];
        }
    } else if (blk < EDGE_BLKS + EC_BLKS + HABS_BLKS + GATE_BLKS + TRANS_BLKS) {
        __half* lds = (__half*)smem;
        int tb = blk - (EDGE_BLKS + EC_BLKS + HABS_BLKS + GATE_BLKS);
        int nt = tb % 72, kt = tb / 72;
        int n0 = nt*64, k0 = kt*64;
        for (int p = 0; p < 16; p++) {
            int idx = t + 256*p;
            int kk = idx >> 6, nn = idx & 63;
            lds[nn*66 + kk] = __float2half(rw2[(k0+kk)*WNUM + n0+nn]);
        }
        __syncthreads();
        for (int p = 0; p < 16; p++) {
            int idx = t + 256*p;
            int nn = idx >> 6, kk = idx & 63;
            rw2T[(n0+nn)*HID + k0+kk] = lds[nn*66 + kk];
        }
    } else {
        for (int p = 0; p < 6; p++) inv[t + 256*p] = -1;
        for (int p = 0; p < 4; p++) {
            int e = t + 256*p;
            float d = att_dist[e];
            envE[e] = (d < CUTOFF) ? 0.5f*(cosf(3.14159265358979323846f*d/CUTOFF) + 1.0f) : 0.0f;
            float vx = att_vec[3*e], vy = att_vec[3*e+1], vz = att_vec[3*e+2];
            float nrm = sqrtf(vx*vx + vy*vy + vz*vz);
            float is = 1.0f / fmaxf(nrm, 1e-8f);
            const float s3 = 1.7320508075688772f;
            y1E[3*e]   = s3*vx*is;
            y1E[3*e+1] = s3*vy*is;
            y1E[3*e+2] = s3*vz*is;
        }
        __syncthreads();
        for (int p = 0; p < 4; p++) { int e = t + 256*p; inv[att_dst[e]] = e; }
    }
}

// ---------------- MFMA tpw GEMM + q layers 2-3 (unchanged) ----------------
__global__ __launch_bounds__(256) void k_mq(
    const __half* __restrict__ hiddenH, const __half* __restrict__ rw2T,
    const float* __restrict__ rb2,
    const float* __restrict__ habs1, const float* __restrict__ ec, const float* __restrict__ qb1,
    const float* __restrict__ qw2, const float* __restrict__ qb2,
    const float* __restrict__ qw3, const float* __restrict__ qb3,
    __half* __restrict__ tpwE, float* __restrict__ qmat)
{
    __shared__ __align__(16) char smemraw[17408];
    int blk = blockIdx.x;
    int t = threadIdx.x;
    if (blk < MFMA_BLKS) {
        int colTile = blk % 36;
        int rowGrp  = blk / 36;
        int wv = t >> 6;
        int lane = t & 63;
        int m0 = (rowGrp*4 + wv) * 16;
        int n0 = colTile * 128;
        int mrow = lane & 15, quad = lane >> 4;
        __half* cS = (__half*)smemraw + wv * (16*136);
        const _Float16* hp = (const _Float16*)hiddenH + (m0 + mrow)*HID + quad*8;
        half8_t af[4];
        #pragma unroll
        for (int kc = 0; kc < 4; kc++) af[kc] = *(const half8_t*)(hp + kc*32);
        #pragma unroll
        for (int nt = 0; nt < 8; nt++) {
            const _Float16* bp = (const _Float16*)rw2T + (n0 + nt*16 + mrow)*HID + quad*8;
            float4v acc = {0.f, 0.f, 0.f, 0.f};
            #pragma unroll
            for (int kc = 0; kc < 4; kc++) {
                half8_t bf = *(const half8_t*)(bp + kc*32);
                acc = __builtin_amdgcn_mfma_f32_16x16x32_f16(af[kc], bf, acc, 0, 0, 0);
            }
            float bias = rb2[n0 + nt*16 + mrow];
            #pragma unroll
            for (int r = 0; r < 4; r++)
                cS[(quad*4 + r)*136 + nt*16 + mrow] = __float2half(acc[r] + bias);
        }
        #pragma unroll
        for (int p = 0; p < 4; p++) {
            int chunk = lane + 64*p;
            int row = chunk >> 4, c8 = (chunk & 15)*8;
            float4 v = *(float4*)&cS[row*136 + c8];
            *(float4*)&tpwE[(long)(m0 + row)*WNUM + n0 + c8] = v;
        }
    } else {
        float* l1S = (float*)smemraw;
        float* l2S = (float*)smemraw + 1024;
        int r0 = (blk - MFMA_BLKS) * 8;
        for (int p = 0; p < 4; p++) {
            int idx = t + 256*p;
            int rr = idx >> 7, i = idx & 127;
            int be = r0 + rr; int b = be >> 8; int e = be & 255;
            l1S[rr*128 + i] = silu_f(habs1[b*HID + i] + ec[e*HID + i] + qb1[i]);
        }
        __syncthreads();
        int r = t >> 5, c0 = (t & 31)*4;
        {
            float4 a0 = *(const float4*)&qb2[c0];
            float4 a1 = make_float4(0,0,0,0);
            #pragma unroll 8
            for (int i = 0; i < HID; i += 2) {
                float x0v = l1S[r*128 + i], x1v = l1S[r*128 + i+1];
                float4 w0 = *(const float4*)&qw2[i*HID + c0];
                float4 w1 = *(const float4*)&qw2[(i+1)*HID + c0];
                a0.x += x0v*w0.x; a0.y += x0v*w0.y; a0.z += x0v*w0.z; a0.w += x0v*w0.w;
                a1.x += x1v*w1.x; a1.y += x1v*w1.y; a1.z += x1v*w1.z; a1.w += x1v*w1.w;
            }
            l2S[r*128 + c0]   = silu_f(a0.x + a1.x); l2S[r*128 + c0+1] = silu_f(a0.y + a1.y);
            l2S[r*128 + c0+2] = silu_f(a0.z + a1.z); l2S[r*128 + c0+3] = silu_f(a0.w + a1.w);
        }
        __syncthreads();
        {
            float4 a0 = *(const float4*)&qb3[c0];
            float4 a1 = make_float4(0,0,0,0);
            #pragma unroll 8
            for (int i = 0; i < HID; i += 2) {
                float x0v = l2S[r*128 + i], x1v = l2S[r*128 + i+1];
                float4 w0 = *(const float4*)&qw3[i*HID + c0];
                float4 w1 = *(const float4*)&qw3[(i+1)*HID + c0];
                a0.x += x0v*w0.x; a0.y += x0v*w0.y; a0.z += x0v*w0.z; a0.w += x0v*w0.w;
                a1.x += x1v*w1.x; a1.y += x1v*w1.y; a1.z += x1v*w1.z; a1.w += x1v*w1.w;
            }
            float4 o;
            o.x = a0.x + a1.x; o.y = a0.y + a1.y; o.z = a0.z + a1.z; o.w = a0.w + a1.w;
            *(float4*)&qmat[(r0 + r)*LAT + c0] = o;
        }
    }
}

// ---------------- merged scores GEMM (float4 LDS reads) + tensor product ----------------
__global__ __launch_bounds__(256) void k_st(
    const float* __restrict__ qmat, const float* __restrict__ kmat, const int* __restrict__ inv,
    const float* __restrict__ h_full, const __half* __restrict__ tpwE,
    const int* __restrict__ att_dst,
    const float* __restrict__ envE, const float* __restrict__ y1E,
    float* __restrict__ scoresW, float* __restrict__ virr)
{
    __shared__ float smem[8544];
    int blk = blockIdx.x;
    int t = threadIdx.x;
    if (blk < SCORE_BLKS) {
        int b  = blk >> 3;
        int e0 = (blk & 7) * 32;
        float (*Qs)[132] = (float(*)[132])smem;
        float (*Kt)[132] = (float(*)[132])(smem + 32*132);
        float* mS = smem + 2*32*132;
        for (int p = 0; p < 4; p++) {
            int idx = t + 256*p; int e = idx >> 5, i4 = idx & 31;
            *(float4*)&Qs[e][i4*4] = *(const float4*)&qmat[(b*NE + e0 + e)*LAT + i4*4];
        }
        if (t < NN) mS[t] = ((unsigned)inv[b*NN + t] < E_ATT) ? 1.0f : 0.0f;
        int te = t >> 5, tn = t & 31;
        float acc[4][3] = {};
        for (int nt = 0; nt < 3; nt++) {
            __syncthreads();
            for (int p = 0; p < 4; p++) {
                int idx = t + 256*p; int n = idx >> 5, i4 = idx & 31;
                *(float4*)&Kt[n][i4*4] = *(const float4*)&kmat[(b*NN + nt*32 + n)*LAT + i4*4];
            }
            __syncthreads();
            // float4 LDS reads: 5 x b128 per 16 FMAs (was 5 x b32 per 4)
            for (int i = 0; i < LAT; i += 4) {
                float4 kv = *(float4*)&Kt[tn][i];
                #pragma unroll
                for (int j = 0; j < 4; j++) {
                    float4 qv = *(float4*)&Qs[te*4 + j][i];
                    acc[j][nt] += qv.x*kv.x + qv.y*kv.y + qv.z*kv.z + qv.w*kv.w;
                }
            }
        }
        const float scale = 0.04419417382415922f;  // (1/HEADS)*HD^-0.5
        #pragma unroll
        for (int j = 0; j < 4; j++)
            #pragma unroll
            for (int jj = 0; jj < 3; jj++) {
                int n = tn + 32*jj;
                float s = (mS[n] != 0.f) ? acc[j][jj]*scale : -1e9f;
                scoresW[((b*NE) + e0 + te*4 + j)*NN + n] = s;
            }
    } else {
        int sub = t >> 7, tt = t & 127;
        int e = (blk - SCORE_BLKS)*2 + sub;
        int f = att_dst[e];
        float* x0  = smem + sub*256;
        float* x1f = smem + sub*256 + 64;
        float* xy  = smem + sub*256 + 160;
        float* y1s = smem + sub*256 + 192;
        const float* hf = h_full + f*NODE_DIM;
        if (tt < M0I) x0[tt] = hf[tt];
        if (tt < M1I*3) x1f[tt] = hf[M0I + tt];
        if (tt < 3) y1s[tt] = y1E[3*e + tt];
        __syncthreads();
        if (tt < M1I) xy[tt] = x1f[3*tt]*y1s[0] + x1f[3*tt+1]*y1s[1] + x1f[3*tt+2]*y1s[2];
        __syncthreads();
        float scale = envE[e];
        const __half* w = tpwE + (long)e*WNUM;
        const float alpha = 0.10206207261596575f;  // 1/sqrt(96)
        const float cc = 0.5773502691896258f;      // 1/sqrt(3)
        if (tt < M0O) {
            float t00 = 0.f, t11 = 0.f;
            #pragma unroll 4
            for (int i = 0; i < M0I; i++) t00 += x0[i]*__half2float(w[i*M0O + tt]);
            #pragma unroll 4
            for (int i = 0; i < M1I; i++) t11 += xy[i]*__half2float(w[SEG3 + i*M0O + tt]);
            virr[f*OUT_DIM + tt] = alpha*(t00 + cc*t11)*scale;
        } else if (tt < M0O + 3*M1O) {
            int idx = tt - M0O; int o = idx/3, m = idx - 3*o;
            float t01 = 0.f, t10 = 0.f;
            #pragma unroll 4
            for (int i = 0; i < M0I; i++) t01 += x0[i]*__half2float(w[SEG1 + i*M1O + o]);
            #pragma unroll 4
            for (int i = 0; i < M1I; i++) t10 += x1f[i*3 + m]*__half2float(w[SEG2 + i*M1O + o]);
            virr[f*OUT_DIM + tt] = alpha*cc*(t01*y1s[m] + t10)*scale;
        }
    }
}

// ---------------- fused attention(softmax+PV dual-acc) + final MLP ----------------
__global__ __launch_bounds__(256) void k_attf(
    const float* __restrict__ scoresW, const int* __restrict__ inv,
    const float* __restrict__ virr, const float* __restrict__ gexp,
    const float* __restrict__ ow1, const float* __restrict__ ob1,
    const float* __restrict__ ow2, const float* __restrict__ ob2,
    const float* __restrict__ ow3, const float* __restrict__ ob3,
    float* __restrict__ out)
{
    int b  = blockIdx.x >> 5;
    int e0 = (blockIdx.x & 31) * 8;
    int t = threadIdx.x;
    __shared__ float aS[8][100];
    __shared__ float gS[8][84];
    __shared__ float ocS[8][84];
    __shared__ float mS[NN];
    __shared__ float inS[8][INVD];
    __shared__ float l1S[8][HID];
    __shared__ float l2S[8][HID];

    for (int p = 0; p < 3; p++) {
        int idx = t + 256*p;
        int el = idx / NN, n = idx - NN*(idx/NN);
        aS[el][n] = scoresW[((b*NE) + e0 + el)*NN + n];
    }
    if (t < 160) {
        int el = t / 20, c4 = t - 20*(t/20);
        *(float4*)&gS[el][c4*4] = *(const float4*)&gexp[(e0 + el)*OUT_DIM + c4*4];
    }
    if (t < NN) mS[t] = ((unsigned)inv[b*NN + t] < E_ATT) ? 1.0f : 0.0f;
    __syncthreads();

    {
        int el = t >> 5;
        int ng = t & 31;
        float s0 = aS[el][ng], s1 = aS[el][ng + 32], s2 = aS[el][ng + 64];
        float m0 = mS[ng], m1 = mS[ng + 32], m2 = mS[ng + 64];
        float mx = fmaxf(s0, fmaxf(s1, s2));
        #pragma unroll
        for (int off = 1; off < 32; off <<= 1) mx = fmaxf(mx, __shfl_xor(mx, off));
        float e0v = expf(s0 - mx), e1v = expf(s1 - mx), e2v = expf(s2 - mx);
        float sm = e0v + e1v + e2v;
        #pragma unroll
        for (int off = 1; off < 32; off <<= 1) sm += __shfl_xor(sm, off);
        float r = 1.0f / sm;
        float p0 = m0*e0v*r, p1 = m1*e1v*r, p2 = m2*e2v*r;
        float ss = p0 + p1 + p2;
        #pragma unroll
        for (int off = 1; off < 32; off <<= 1) ss += __shfl_xor(ss, off);
        float is = 1.0f / fmaxf(ss, 1e-8f);
        aS[el][ng]      = p0*is;
        aS[el][ng + 32] = p1*is;
        aS[el][ng + 64] = p2*is;
    }
    __syncthreads();

    // PV: dual accumulator halves the dependent FMA chain (96 -> 48)
    if (t < 160) {
        int el = t / 20, c4 = t - 20*(t/20);
        const float* vp = virr + (long)b*NN*OUT_DIM + c4*4;
        float4 accA = make_float4(0,0,0,0);
        float4 accB = make_float4(0,0,0,0);
        #pragma unroll 4
        for (int n = 0; n < 48; n++) {
            float a0 = aS[el][n];
            float4 v0 = *(const float4*)&vp[n*OUT_DIM];
            accA.x += a0*v0.x; accA.y += a0*v0.y; accA.z += a0*v0.z; accA.w += a0*v0.w;
            float a1 = aS[el][48 + n];
            float4 v1 = *(const float4*)&vp[(48 + n)*OUT_DIM];
            accB.x += a1*v1.x; accB.y += a1*v1.y; accB.z += a1*v1.z; accB.w += a1*v1.w;
        }
        float4 g = *(float4*)&gS[el][c4*4];
        float4 o;
        o.x = (accA.x + accB.x)*g.x; o.y = (accA.y + accB.y)*g.y;
        o.z = (accA.z + accB.z)*g.z; o.w = (accA.w + accB.w)*g.w;
        *(float4*)&ocS[el][c4*4] = o;
    }
    __syncthreads();

    for (int u = t; u < 8*INVD; u += 256) {
        int el = u / INVD, j = u - INVD*(u/INVD);
        float val;
        if (j < M0O) val = ocS[el][j];
        else {
            int o = j - M0O;
            float x = ocS[el][M0O + 3*o], y = ocS[el][M0O + 3*o + 1], zz = ocS[el][M0O + 3*o + 2];
            val = sqrtf(x*x + y*y + zz*zz + 1e-12f);
        }
        inS[el][j] = val;
    }
    __syncthreads();

    int r = t >> 5, c0 = (t & 31)*4;
    {
        float4 a0 = *(const float4*)&ob1[c0];
        float4 a1 = make_float4(0,0,0,0);
        #pragma unroll 8
        for (int i = 0; i < INVD; i += 2) {
            float x0v = inS[r][i], x1v = inS[r][i+1];
            float4 w0 = *(const float4*)&ow1[i*HID + c0];
            float4 w1 = *(const float4*)&ow1[(i+1)*HID + c0];
            a0.x += x0v*w0.x; a0.y += x0v*w0.y; a0.z += x0v*w0.z; a0.w += x0v*w0.w;
            a1.x += x1v*w1.x; a1.y += x1v*w1.y; a1.z += x1v*w1.z; a1.w += x1v*w1.w;
        }
        l1S[r][c0]   = silu_f(a0.x + a1.x); l1S[r][c0+1] = silu_f(a0.y + a1.y);
        l1S[r][c0+2] = silu_f(a0.z + a1.z); l1S[r][c0+3] = silu_f(a0.w + a1.w);
    }
    __syncthreads();
    {
        float4 a0 = *(const float4*)&ob2[c0];
        float4 a1 = make_float4(0,0,0,0);
        #pragma unroll 8
        for (int i = 0; i < HID; i += 2) {
            float x0v = l1S[r][i], x1v = l1S[r][i+1];
            float4 w0 = *(const float4*)&ow2[i*HID + c0];
            float4 w1 = *(const float4*)&ow2[(i+1)*HID + c0];
            a0.x += x0v*w0.x; a0.y += x0v*w0.y; a0.z += x0v*w0.z; a0.w += x0v*w0.w;
            a1.x += x1v*w1.x; a1.y += x1v*w1.y; a1.z += x1v*w1.z; a1.w += x1v*w1.w;
        }
        l2S[r][c0]   = silu_f(a0.x + a1.x); l2S[r][c0+1] = silu_f(a0.y + a1.y);
        l2S[r][c0+2] = silu_f(a0.z + a1.z); l2S[r][c0+3] = silu_f(a0.w + a1.w);
    }
    __syncthreads();
    {
        float4 a0 = *(const float4*)&ob3[c0];
        float4 a1 = make_float4(0,0,0,0);
        #pragma unroll 8
        for (int i = 0; i < HID; i += 2) {
            float x0v = l2S[r][i], x1v = l2S[r][i+1];
            float4 w0 = *(const float4*)&ow3[i*HID + c0];
            float4 w1 = *(const float4*)&ow3[(i+1)*HID + c0];
            a0.x += x0v*w0.x; a0.y += x0v*w0.y; a0.z += x0v*w0.z; a0.w += x0v*w0.w;
            a1.x += x1v*w1.x; a1.y += x1v*w1.y; a1.z += x1v*w1.z; a1.w += x1v*w1.w;
        }
        float4 o;
        o.x = a0.x + a1.x; o.y = a0.y + a1.y; o.z = a0.z + a1.z; o.w = a0.w + a1.w;
        *(float4*)&out[((b*NE + e0) + r)*LAT + c0] = o;
    }
}

extern "C" void kernel_launch(void* const* d_in, const int* in_sizes, int n_in,
                              void* d_out, int out_size, void* d_ws, size_t ws_size,
                              hipStream_t stream) {
    const float* h        = (const float*)d_in[0];
    const float* h_full   = (const float*)d_in[1];
    const float* e_feat   = (const float*)d_in[2];
    const float* att_dist = (const float*)d_in[3];
    const float* att_vec  = (const float*)d_in[4];
    const float* z_emb    = (const float*)d_in[5];
    const float* rw1 = (const float*)d_in[6];  const float* rb1 = (const float*)d_in[7];
    const float* rw2 = (const float*)d_in[8];  const float* rb2 = (const float*)d_in[9];
    const float* ew1 = (const float*)d_in[10]; const float* eb1 = (const float*)d_in[11];
    const float* ew2 = (const float*)d_in[12]; const float* eb2 = (const float*)d_in[13];
    const float* qw1 = (const float*)d_in[14]; const float* qb1 = (const float*)d_in[15];
    const float* qw2 = (const float*)d_in[16]; const float* qb2 = (const float*)d_in[17];
    const float* qw3 = (const float*)d_in[18]; const float* qb3 = (const float*)d_in[19];
    const float* kw1 = (const float*)d_in[20]; const float* kb1 = (const float*)d_in[21];
    const float* kw2 = (const float*)d_in[22]; const float* kb2 = (const float*)d_in[23];
    const float* kw3 = (const float*)d_in[24]; const float* kb3 = (const float*)d_in[25];
    const float* ow1 = (const float*)d_in[26]; const float* ob1 = (const float*)d_in[27];
    const float* ow2 = (const float*)d_in[28]; const float* ob2 = (const float*)d_in[29];
    const float* ow3 = (const float*)d_in[30]; const float* ob3 = (const float*)d_in[31];
    const int* z        = (const int*)d_in[32];
    const int* absorber = (const int*)d_in[34];
    const int* att_dst  = (const int*)d_in[35];

    float* ws = (float*)d_ws;
    int*   inv     = (int*)ws;                    // 1536
    float* y1E     = ws + 1536;                   // 3072
    float* envE    = ws + 4608;                   // 1024
    float* kmat    = ws + 5632;                   // 196608 (1536x128)
    float* qmat    = ws + 202240;                 // 524288 (4096x128)
    float* gexp    = ws + 726528;                 // 20480
    float* virr    = ws + 747008;                 // 122880 (1536x80)
    float* habs1   = ws + 869888;                 // 2048
    float* ec      = ws + 871936;                 // 32768
    float* scoresW = ws + 904704;                 // 393216 (4096x96)
    __half* tpwE   = (__half*)(ws + 1297920);     // 4718592 halves
    __half* rw2T   = (__half*)(ws + 3657216);     // 589824 halves (4608x128)
    __half* hiddenH= (__half*)(ws + 3952128);     // 131072 halves (1024x128)

    float* out = (float*)d_out;

    k_stage1<<<STAGE1_BLKS, 256, 0, stream>>>(h, z_emb, z, absorber, e_feat,
                                              att_dst, att_dist, att_vec,
                                              rw1, rb1, kw1, kb1, kw2, kb2, kw3, kb3,
                                              qw1, ew1, eb1, ew2, eb2, rw2,
                                              hiddenH, kmat, ec, habs1, gexp, rw2T,
                                              inv, y1E, envE);
    k_mq<<<MQ_BLKS, 256, 0, stream>>>(hiddenH, rw2T, rb2, habs1, ec, qb1,
                                      qw2, qb2, qw3, qb3, tpwE, qmat);
    k_st<<<ST_BLKS, 256, 0, stream>>>(qmat, kmat, inv, h_full, tpwE, att_dst,
                                      envE, y1E, scoresW, virr);
    k_attf<<<BB*32, 256, 0, stream>>>(scoresW, inv, virr, gexp,
                                      ow1, ob1, ow2, ob2, ow3, ob3, out);
}

// Round 16
// 235.387 us; speedup vs baseline: 1.1223x; 1.1223x over previous
//
#include <hip/hip_runtime.h>
#include <hip/hip_fp16.h>
#include <math.h>

#define BB 16
#define NN 96
#define NE 256
#define FF (BB*NN)      // 1536
#define ATOM 128
#define EDIM 16
#define HID 128
#define LAT 128
#define RBFN 16
#define CUTOFF 5.0f
#define ZEMB 32
#define E_ATT 1024
#define M0I 64
#define M1I 32
#define M0O 32
#define M1O 16
#define NODE_DIM 160
#define OUT_DIM 80
#define INVD 48
#define WNUM 4608
#define SEG1 2048
#define SEG2 3072
#define SEG3 3584

#define EDGE_BLKS (E_ATT/4)  // 256 (4 edges/block, wave = edge)
#define EC_BLKS 16
#define HABS_BLKS 2
#define GATE_BLKS 16
#define TRANS_BLKS 144
#define PREP_BLKS 1
#define STAGE1_BLKS (EDGE_BLKS + EC_BLKS + HABS_BLKS + GATE_BLKS + TRANS_BLKS + PREP_BLKS)  // 435

#define MFMA_BLKS (36*16)  // 576
#define MQ_BLKS (MFMA_BLKS + 512)

#define SCORE_BLKS 128
#define ST_BLKS (SCORE_BLKS + 512)

typedef _Float16 half8_t __attribute__((ext_vector_type(8)));
typedef float float4v __attribute__((ext_vector_type(4)));

__device__ __forceinline__ float silu_f(float x) { return x / (1.0f + expf(-x)); }

// ---------------- stage1 mega-kernel ----------------
// [0,256): edge pipeline (4 edges/block, wave = edge: features + hidden + k-MLP)
// [256,272): ec; [272,274): habs1; [274,290): gates; [290,434): rw2->rw2T; [434]: prep
__global__ __launch_bounds__(256) void k_stage1(
    const float* __restrict__ h, const float* __restrict__ z_emb, const int* __restrict__ z,
    const int* __restrict__ absorber, const float* __restrict__ e_feat,
    const int* __restrict__ att_dst, const float* __restrict__ att_dist,
    const float* __restrict__ att_vec,
    const float* __restrict__ rw1, const float* __restrict__ rb1,
    const float* __restrict__ kw1, const float* __restrict__ kb1,
    const float* __restrict__ kw2, const float* __restrict__ kb2,
    const float* __restrict__ kw3, const float* __restrict__ kb3,
    const float* __restrict__ qw1,
    const float* __restrict__ ew1, const float* __restrict__ eb1,
    const float* __restrict__ ew2, const float* __restrict__ eb2,
    const float* __restrict__ rw2,
    __half* __restrict__ hiddenH, float* __restrict__ kmatw,
    float* __restrict__ ecw, float* __restrict__ habs1w, float* __restrict__ gexp,
    __half* __restrict__ rw2T,
    int* __restrict__ inv, float* __restrict__ y1E, float* __restrict__ envE)
{
    __shared__ float smem[3488];
    int blk = blockIdx.x;
    int t = threadIdx.x;

    if (blk < EDGE_BLKS) {
        float (*sin1)[184] = (float(*)[184])smem;            // 4 x 184 (177 used)
        float (*l1S)[128]  = (float(*)[128])(smem + 736);
        float (*l2S)[128]  = (float(*)[128])(smem + 736 + 512);
        int w = t >> 6;           // wave = edge slot
        int c = t & 63;
        int e = blk*4 + w;
        int f = att_dst[e];
        int b = f / NN, nn = f - b*NN;
        float d = att_dist[e];
        {   // h[f]: 2 floats per lane (coalesced per wave)
            float2 hv = *(const float2*)&h[f*ATOM + 2*c];
            sin1[w][2*c] = hv.x; sin1[w][2*c + 1] = hv.y;
        }
        if (c < ZEMB) sin1[w][ATOM + c] = z_emb[z[f]*ZEMB + c];
        if (c >= 32 && c < 48) {
            int j = c - 32;
            const float delta = CUTOFF / (RBFN - 1);
            float diff = d - j*delta;
            sin1[w][ATOM + ZEMB + 1 + j] = expf(-diff*diff / (2.0f*delta*delta));
        }
        if (c == 48) sin1[w][ATOM + ZEMB] = (absorber[b] == nn) ? 1.0f : 0.0f;
        __syncthreads();
        int c2 = 2*c;
        {   // hidden = silu(w_in @ rw1 + rb1): 49 -> 128 (edge-indexed)
            float2 a0 = *(const float2*)&rb1[c2];
            float2 a1 = make_float2(0.f, 0.f);
            #pragma unroll 8
            for (int i = 0; i < 48; i += 2) {
                float x0v = sin1[w][ATOM + i], x1v = sin1[w][ATOM + i + 1];
                float2 w0 = *(const float2*)&rw1[i*HID + c2];
                float2 w1 = *(const float2*)&rw1[(i+1)*HID + c2];
                a0.x += x0v*w0.x; a0.y += x0v*w0.y;
                a1.x += x1v*w1.x; a1.y += x1v*w1.y;
            }
            {
                float x0v = sin1[w][ATOM + 48];
                float2 w0 = *(const float2*)&rw1[48*HID + c2];
                a0.x += x0v*w0.x; a0.y += x0v*w0.y;
            }
            *(__half2*)&hiddenH[e*HID + c2] =
                __floats2half2_rn(silu_f(a0.x + a1.x), silu_f(a0.y + a1.y));
        }
        {   // k layer 1: 177 -> 128
            float2 a0 = *(const float2*)&kb1[c2];
            float2 a1 = make_float2(0.f, 0.f);
            #pragma unroll 8
            for (int i = 0; i < 176; i += 2) {
                float x0v = sin1[w][i], x1v = sin1[w][i + 1];
                float2 w0 = *(const float2*)&kw1[i*HID + c2];
                float2 w1 = *(const float2*)&kw1[(i+1)*HID + c2];
                a0.x += x0v*w0.x; a0.y += x0v*w0.y;
                a1.x += x1v*w1.x; a1.y += x1v*w1.y;
            }
            {
                float x0v = sin1[w][176];
                float2 w0 = *(const float2*)&kw1[176*HID + c2];
                a0.x += x0v*w0.x; a0.y += x0v*w0.y;
            }
            l1S[w][c2] = silu_f(a0.x + a1.x); l1S[w][c2+1] = silu_f(a0.y + a1.y);
        }
        __syncthreads();
        {   // k layer 2
            float2 a0 = *(const float2*)&kb2[c2];
            float2 a1 = make_float2(0.f, 0.f);
            #pragma unroll 8
            for (int i = 0; i < HID; i += 2) {
                float x0v = l1S[w][i], x1v = l1S[w][i + 1];
                float2 w0 = *(const float2*)&kw2[i*HID + c2];
                float2 w1 = *(const float2*)&kw2[(i+1)*HID + c2];
                a0.x += x0v*w0.x; a0.y += x0v*w0.y;
                a1.x += x1v*w1.x; a1.y += x1v*w1.y;
            }
            l2S[w][c2] = silu_f(a0.x + a1.x); l2S[w][c2+1] = silu_f(a0.y + a1.y);
        }
        __syncthreads();
        {   // k layer 3 -> kmat (node-indexed, attended rows only)
            float2 a0 = *(const float2*)&kb3[c2];
            float2 a1 = make_float2(0.f, 0.f);
            #pragma unroll 8
            for (int i = 0; i < HID; i += 2) {
                float x0v = l2S[w][i], x1v = l2S[w][i + 1];
                float2 w0 = *(const float2*)&kw3[i*HID + c2];
                float2 w1 = *(const float2*)&kw3[(i+1)*HID + c2];
                a0.x += x0v*w0.x; a0.y += x0v*w0.y;
                a1.x += x1v*w1.x; a1.y += x1v*w1.y;
            }
            float2 o; o.x = a0.x + a1.x; o.y = a0.y + a1.y;
            *(float2*)&kmatw[f*HID + c2] = o;
        }
    } else if (blk < EDGE_BLKS + EC_BLKS) {
        float (*ef)[16] = (float(*)[16])smem;
        int e0 = (blk - EDGE_BLKS) * 16;
        { int e = t >> 4, i = t & 15; ef[e][i] = e_feat[(e0 + e)*EDIM + i]; }
        __syncthreads();
        int r = t >> 4, c0 = (t & 15)*8;
        float4 a0 = make_float4(0,0,0,0), a1 = a0;
        #pragma unroll
        for (int i = 0; i < EDIM; i++) {
            float a = ef[r][i];
            float4 w0 = *(const float4*)&qw1[(ATOM + i)*HID + c0];
            float4 w1 = *(const float4*)&qw1[(ATOM + i)*HID + c0 + 4];
            a0.x += a*w0.x; a0.y += a*w0.y; a0.z += a*w0.z; a0.w += a*w0.w;
            a1.x += a*w1.x; a1.y += a*w1.y; a1.z += a*w1.z; a1.w += a*w1.w;
        }
        *(float4*)&ecw[(e0 + r)*HID + c0] = a0;
        *(float4*)&ecw[(e0 + r)*HID + c0 + 4] = a1;
    } else if (blk < EDGE_BLKS + EC_BLKS + HABS_BLKS) {
        float (*hr)[128] = (float(*)[128])smem;
        int b0 = (blk - EDGE_BLKS - EC_BLKS) * 8;
        {
            int r = t >> 5, i4 = t & 31;
            int b = b0 + r;
            int a = absorber[b];
            *(float4*)&hr[r][i4*4] = *(const float4*)&h[(b*NN + a)*ATOM + i4*4];
        }
        __syncthreads();
        int r = t >> 5, c0 = (t & 31)*4;
        float4 a0 = make_float4(0,0,0,0), a1 = a0;
        #pragma unroll 8
        for (int i = 0; i < ATOM; i += 2) {
            float x0v = hr[r][i], x1v = hr[r][i+1];
            float4 w0 = *(const float4*)&qw1[i*HID + c0];
            float4 w1 = *(const float4*)&qw1[(i+1)*HID + c0];
            a0.x += x0v*w0.x; a0.y += x0v*w0.y; a0.z += x0v*w0.z; a0.w += x0v*w0.w;
            a1.x += x1v*w1.x; a1.y += x1v*w1.y; a1.z += x1v*w1.z; a1.w += x1v*w1.w;
        }
        float4 o;
        o.x = a0.x + a1.x; o.y = a0.y + a1.y; o.z = a0.z + a1.z; o.w = a0.w + a1.w;
        *(float4*)&habs1w[(b0 + r)*HID + c0] = o;
    } else if (blk < EDGE_BLKS + EC_BLKS + HABS_BLKS + GATE_BLKS) {
        float (*ef)[16]   = (float(*)[16])smem;
        float (*l1g)[128] = (float(*)[128])(smem + 256);
        float (*gg)[48]   = (float(*)[48])(smem + 256 + 2048);
        int e0 = (blk - EDGE_BLKS - EC_BLKS - HABS_BLKS) * 16;
        { int e = t >> 4, i = t & 15; ef[e][i] = e_feat[(e0 + e)*EDIM + i]; }
        __syncthreads();
        int r = t >> 4, c0 = (t & 15)*8;
        {
            float4 a0 = *(const float4*)&eb1[c0];
            float4 a1 = *(const float4*)&eb1[c0 + 4];
            #pragma unroll
            for (int i = 0; i < EDIM; i++) {
                float a = ef[r][i];
                float4 w0 = *(const float4*)&ew1[i*HID + c0];
                float4 w1 = *(const float4*)&ew1[i*HID + c0 + 4];
                a0.x += a*w0.x; a0.y += a*w0.y; a0.z += a*w0.z; a0.w += a*w0.w;
                a1.x += a*w1.x; a1.y += a*w1.y; a1.z += a*w1.z; a1.w += a*w1.w;
            }
            l1g[r][c0]   = silu_f(a0.x); l1g[r][c0+1] = silu_f(a0.y);
            l1g[r][c0+2] = silu_f(a0.z); l1g[r][c0+3] = silu_f(a0.w);
            l1g[r][c0+4] = silu_f(a1.x); l1g[r][c0+5] = silu_f(a1.y);
            l1g[r][c0+6] = silu_f(a1.z); l1g[r][c0+7] = silu_f(a1.w);
        }
        __syncthreads();
        for (int u = t; u < 16*48; u += 256) {
            int e = u / 48, j = u - 48*(u/48);
            float acc = eb2[j];
            #pragma unroll 4
            for (int i = 0; i < HID; i++) acc += l1g[e][i]*ew2[i*48 + j];
            gg[e][j] = acc;
        }
        __syncthreads();
        for (int u = t; u < 16*80; u += 256) {
            int e = u / 80, cc = u - 80*(u/80);
            gexp[(e0 + e)*OUT_DIM + cc] = (cc < M0O) ? gg[e][cc] : gg[e][M0O + (cc - M0O)/3];
        }
    } else if (blk < EDGE_BLKS + EC_BLKS + HABS_BLKS + GATE_BLKS + TRANS_BLKS) {
        __half* lds = (__half*)smem;  // [64][66]
        int tb = blk - (EDGE_BLKS + EC_BLKS + HABS_BLKS + GATE_BLKS);
        int nt = tb % 72, kt = tb / 72;
        int n0 = nt*64, k0 = kt*64;
        for (int p = 0; p < 16; p++) {
            int idx = t + 256*p;
            int kk = idx >> 6, nn = idx & 63;
            lds[nn*66 + kk] = __float2half(rw2[(k0+kk)*WNUM + n0+nn]);
        }
        __syncthreads();
        for (int p = 0; p < 16; p++) {
            int idx = t + 256*p;
            int nn = idx >> 6, kk = idx & 63;
            rw2T[(n0+nn)*HID + k0+kk] = lds[nn*66 + kk];
        }
    } else {
        // prep: inv init + per-edge y1/env + scatter
        for (int p = 0; p < 6; p++) inv[t + 256*p] = -1;
        for (int p = 0; p < 4; p++) {
            int e = t + 256*p;
            float d = att_dist[e];
            envE[e] = (d < CUTOFF) ? 0.5f*(cosf(3.14159265358979323846f*d/CUTOFF) + 1.0f) : 0.0f;
            float vx = att_vec[3*e], vy = att_vec[3*e+1], vz = att_vec[3*e+2];
            float nrm = sqrtf(vx*vx + vy*vy + vz*vz);
            float is = 1.0f / fmaxf(nrm, 1e-8f);
            const float s3 = 1.7320508075688772f;
            y1E[3*e]   = s3*vx*is;
            y1E[3*e+1] = s3*vy*is;
            y1E[3*e+2] = s3*vz*is;
        }
        __syncthreads();
        for (int p = 0; p < 4; p++) { int e = t + 256*p; inv[att_dst[e]] = e; }
    }
}

// ---------------- MFMA tpw GEMM + q layers 2-3 ----------------
__global__ __launch_bounds__(256) void k_mq(
    const __half* __restrict__ hiddenH, const __half* __restrict__ rw2T,
    const float* __restrict__ rb2,
    const float* __restrict__ habs1, const float* __restrict__ ec, const float* __restrict__ qb1,
    const float* __restrict__ qw2, const float* __restrict__ qb2,
    const float* __restrict__ qw3, const float* __restrict__ qb3,
    __half* __restrict__ tpwE, float* __restrict__ qmat)
{
    __shared__ __align__(16) char smemraw[17408];
    int blk = blockIdx.x;
    int t = threadIdx.x;
    if (blk < MFMA_BLKS) {
        int colTile = blk % 36;
        int rowGrp  = blk / 36;
        int wv = t >> 6;
        int lane = t & 63;
        int m0 = (rowGrp*4 + wv) * 16;
        int n0 = colTile * 128;
        int mrow = lane & 15, quad = lane >> 4;
        __half* cS = (__half*)smemraw + wv * (16*136);
        const _Float16* hp = (const _Float16*)hiddenH + (m0 + mrow)*HID + quad*8;
        half8_t af[4];
        #pragma unroll
        for (int kc = 0; kc < 4; kc++) af[kc] = *(const half8_t*)(hp + kc*32);
        #pragma unroll
        for (int nt = 0; nt < 8; nt++) {
            const _Float16* bp = (const _Float16*)rw2T + (n0 + nt*16 + mrow)*HID + quad*8;
            float4v acc = {0.f, 0.f, 0.f, 0.f};
            #pragma unroll
            for (int kc = 0; kc < 4; kc++) {
                half8_t bf = *(const half8_t*)(bp + kc*32);
                acc = __builtin_amdgcn_mfma_f32_16x16x32_f16(af[kc], bf, acc, 0, 0, 0);
            }
            float bias = rb2[n0 + nt*16 + mrow];
            #pragma unroll
            for (int r = 0; r < 4; r++)
                cS[(quad*4 + r)*136 + nt*16 + mrow] = __float2half(acc[r] + bias);
        }
        #pragma unroll
        for (int p = 0; p < 4; p++) {
            int chunk = lane + 64*p;
            int row = chunk >> 4, c8 = (chunk & 15)*8;
            float4 v = *(float4*)&cS[row*136 + c8];
            *(float4*)&tpwE[(long)(m0 + row)*WNUM + n0 + c8] = v;
        }
    } else {
        float* l1S = (float*)smemraw;
        float* l2S = (float*)smemraw + 1024;
        int r0 = (blk - MFMA_BLKS) * 8;
        for (int p = 0; p < 4; p++) {
            int idx = t + 256*p;
            int rr = idx >> 7, i = idx & 127;
            int be = r0 + rr; int b = be >> 8; int e = be & 255;
            l1S[rr*128 + i] = silu_f(habs1[b*HID + i] + ec[e*HID + i] + qb1[i]);
        }
        __syncthreads();
        int r = t >> 5, c0 = (t & 31)*4;
        {
            float4 a0 = *(const float4*)&qb2[c0];
            float4 a1 = make_float4(0,0,0,0);
            #pragma unroll 8
            for (int i = 0; i < HID; i += 2) {
                float x0v = l1S[r*128 + i], x1v = l1S[r*128 + i+1];
                float4 w0 = *(const float4*)&qw2[i*HID + c0];
                float4 w1 = *(const float4*)&qw2[(i+1)*HID + c0];
                a0.x += x0v*w0.x; a0.y += x0v*w0.y; a0.z += x0v*w0.z; a0.w += x0v*w0.w;
                a1.x += x1v*w1.x; a1.y += x1v*w1.y; a1.z += x1v*w1.z; a1.w += x1v*w1.w;
            }
            l2S[r*128 + c0]   = silu_f(a0.x + a1.x); l2S[r*128 + c0+1] = silu_f(a0.y + a1.y);
            l2S[r*128 + c0+2] = silu_f(a0.z + a1.z); l2S[r*128 + c0+3] = silu_f(a0.w + a1.w);
        }
        __syncthreads();
        {
            float4 a0 = *(const float4*)&qb3[c0];
            float4 a1 = make_float4(0,0,0,0);
            #pragma unroll 8
            for (int i = 0; i < HID; i += 2) {
                float x0v = l2S[r*128 + i], x1v = l2S[r*128 + i+1];
                float4 w0 = *(const float4*)&qw3[i*HID + c0];
                float4 w1 = *(const float4*)&qw3[(i+1)*HID + c0];
                a0.x += x0v*w0.x; a0.y += x0v*w0.y; a0.z += x0v*w0.z; a0.w += x0v*w0.w;
                a1.x += x1v*w1.x; a1.y += x1v*w1.y; a1.z += x1v*w1.z; a1.w += x1v*w1.w;
            }
            float4 o;
            o.x = a0.x + a1.x; o.y = a0.y + a1.y; o.z = a0.z + a1.z; o.w = a0.w + a1.w;
            *(float4*)&qmat[(r0 + r)*LAT + c0] = o;
        }
    }
}

// ---------------- merged scores GEMM + tensor product (R14/R13 proven version) ----------------
__global__ __launch_bounds__(256) void k_st(
    const float* __restrict__ qmat, const float* __restrict__ kmat, const int* __restrict__ inv,
    const float* __restrict__ h_full, const __half* __restrict__ tpwE,
    const int* __restrict__ att_dst,
    const float* __restrict__ envE, const float* __restrict__ y1E,
    float* __restrict__ scoresW, float* __restrict__ virr)
{
    __shared__ float smem[8544];
    int blk = blockIdx.x;
    int t = threadIdx.x;
    if (blk < SCORE_BLKS) {
        int b  = blk >> 3;
        int e0 = (blk & 7) * 32;
        float (*Qs)[132] = (float(*)[132])smem;
        float (*Kt)[132] = (float(*)[132])(smem + 32*132);
        float* mS = smem + 2*32*132;
        for (int p = 0; p < 4; p++) {
            int idx = t + 256*p; int e = idx >> 5, i4 = idx & 31;
            *(float4*)&Qs[e][i4*4] = *(const float4*)&qmat[(b*NE + e0 + e)*LAT + i4*4];
        }
        if (t < NN) mS[t] = ((unsigned)inv[b*NN + t] < E_ATT) ? 1.0f : 0.0f;
        int te = t >> 5, tn = t & 31;
        float acc[4][3] = {};
        for (int nt = 0; nt < 3; nt++) {
            __syncthreads();
            for (int p = 0; p < 4; p++) {
                int idx = t + 256*p; int n = idx >> 5, i4 = idx & 31;
                *(float4*)&Kt[n][i4*4] = *(const float4*)&kmat[(b*NN + nt*32 + n)*LAT + i4*4];
            }
            __syncthreads();
            for (int i = 0; i < LAT; i++) {
                float bv = Kt[tn][i];
                acc[0][nt] += Qs[te*4 + 0][i]*bv;
                acc[1][nt] += Qs[te*4 + 1][i]*bv;
                acc[2][nt] += Qs[te*4 + 2][i]*bv;
                acc[3][nt] += Qs[te*4 + 3][i]*bv;
            }
        }
        const float scale = 0.04419417382415922f;  // (1/HEADS)*HD^-0.5
        #pragma unroll
        for (int j = 0; j < 4; j++)
            #pragma unroll
            for (int jj = 0; jj < 3; jj++) {
                int n = tn + 32*jj;
                float s = (mS[n] != 0.f) ? acc[j][jj]*scale : -1e9f;
                scoresW[((b*NE) + e0 + te*4 + j)*NN + n] = s;
            }
    } else {
        int sub = t >> 7, tt = t & 127;
        int e = (blk - SCORE_BLKS)*2 + sub;
        int f = att_dst[e];
        float* x0  = smem + sub*256;
        float* x1f = smem + sub*256 + 64;
        float* xy  = smem + sub*256 + 160;
        float* y1s = smem + sub*256 + 192;
        const float* hf = h_full + f*NODE_DIM;
        if (tt < M0I) x0[tt] = hf[tt];
        if (tt < M1I*3) x1f[tt] = hf[M0I + tt];
        if (tt < 3) y1s[tt] = y1E[3*e + tt];
        __syncthreads();
        if (tt < M1I) xy[tt] = x1f[3*tt]*y1s[0] + x1f[3*tt+1]*y1s[1] + x1f[3*tt+2]*y1s[2];
        __syncthreads();
        float scale = envE[e];
        const __half* w = tpwE + (long)e*WNUM;
        const float alpha = 0.10206207261596575f;  // 1/sqrt(96)
        const float cc = 0.5773502691896258f;      // 1/sqrt(3)
        if (tt < M0O) {
            float t00 = 0.f, t11 = 0.f;
            #pragma unroll 4
            for (int i = 0; i < M0I; i++) t00 += x0[i]*__half2float(w[i*M0O + tt]);
            #pragma unroll 4
            for (int i = 0; i < M1I; i++) t11 += xy[i]*__half2float(w[SEG3 + i*M0O + tt]);
            virr[f*OUT_DIM + tt] = alpha*(t00 + cc*t11)*scale;
        } else if (tt < M0O + 3*M1O) {
            int idx = tt - M0O; int o = idx/3, m = idx - 3*o;
            float t01 = 0.f, t10 = 0.f;
            #pragma unroll 4
            for (int i = 0; i < M0I; i++) t01 += x0[i]*__half2float(w[SEG1 + i*M1O + o]);
            #pragma unroll 4
            for (int i = 0; i < M1I; i++) t10 += x1f[i*3 + m]*__half2float(w[SEG2 + i*M1O + o]);
            virr[f*OUT_DIM + tt] = alpha*cc*(t01*y1s[m] + t10)*scale;
        }
    }
}

// ---------------- fused attention(softmax+PV) + final MLP (R14 proven version) ----------------
__global__ __launch_bounds__(256) void k_attf(
    const float* __restrict__ scoresW, const int* __restrict__ inv,
    const float* __restrict__ virr, const float* __restrict__ gexp,
    const float* __restrict__ ow1, const float* __restrict__ ob1,
    const float* __restrict__ ow2, const float* __restrict__ ob2,
    const float* __restrict__ ow3, const float* __restrict__ ob3,
    float* __restrict__ out)
{
    int b  = blockIdx.x >> 5;
    int e0 = (blockIdx.x & 31) * 8;
    int t = threadIdx.x;
    __shared__ float aS[8][100];
    __shared__ float gS[8][84];
    __shared__ float ocS[8][84];
    __shared__ float mS[NN];
    __shared__ float inS[8][INVD];
    __shared__ float l1S[8][HID];
    __shared__ float l2S[8][HID];

    for (int p = 0; p < 3; p++) {
        int idx = t + 256*p;
        int el = idx / NN, n = idx - NN*(idx/NN);
        aS[el][n] = scoresW[((b*NE) + e0 + el)*NN + n];
    }
    if (t < 160) {
        int el = t / 20, c4 = t - 20*(t/20);
        *(float4*)&gS[el][c4*4] = *(const float4*)&gexp[(e0 + el)*OUT_DIM + c4*4];
    }
    if (t < NN) mS[t] = ((unsigned)inv[b*NN + t] < E_ATT) ? 1.0f : 0.0f;
    __syncthreads();

    {
        int el = t >> 5;
        int ng = t & 31;
        float s0 = aS[el][ng], s1 = aS[el][ng + 32], s2 = aS[el][ng + 64];
        float m0 = mS[ng], m1 = mS[ng + 32], m2 = mS[ng + 64];
        float mx = fmaxf(s0, fmaxf(s1, s2));
        #pragma unroll
        for (int off = 1; off < 32; off <<= 1) mx = fmaxf(mx, __shfl_xor(mx, off));
        float e0v = expf(s0 - mx), e1v = expf(s1 - mx), e2v = expf(s2 - mx);
        float sm = e0v + e1v + e2v;
        #pragma unroll
        for (int off = 1; off < 32; off <<= 1) sm += __shfl_xor(sm, off);
        float r = 1.0f / sm;
        float p0 = m0*e0v*r, p1 = m1*e1v*r, p2 = m2*e2v*r;
        float ss = p0 + p1 + p2;
        #pragma unroll
        for (int off = 1; off < 32; off <<= 1) ss += __shfl_xor(ss, off);
        float is = 1.0f / fmaxf(ss, 1e-8f);
        aS[el][ng]      = p0*is;
        aS[el][ng + 32] = p1*is;
        aS[el][ng + 64] = p2*is;
    }
    __syncthreads();

    if (t < 160) {
        int el = t / 20, c4 = t - 20*(t/20);
        const float* vp = virr + (long)b*NN*OUT_DIM + c4*4;
        float4 acc = make_float4(0,0,0,0);
        #pragma unroll 4
        for (int n = 0; n < NN; n++) {
            float a = aS[el][n];
            float4 v = *(const float4*)&vp[n*OUT_DIM];
            acc.x += a*v.x; acc.y += a*v.y; acc.z += a*v.z; acc.w += a*v.w;
        }
        float4 g = *(float4*)&gS[el][c4*4];
        float4 o; o.x = acc.x*g.x; o.y = acc.y*g.y; o.z = acc.z*g.z; o.w = acc.w*g.w;
        *(float4*)&ocS[el][c4*4] = o;
    }
    __syncthreads();

    for (int u = t; u < 8*INVD; u += 256) {
        int el = u / INVD, j = u - INVD*(u/INVD);
        float val;
        if (j < M0O) val = ocS[el][j];
        else {
            int o = j - M0O;
            float x = ocS[el][M0O + 3*o], y = ocS[el][M0O + 3*o + 1], zz = ocS[el][M0O + 3*o + 2];
            val = sqrtf(x*x + y*y + zz*zz + 1e-12f);
        }
        inS[el][j] = val;
    }
    __syncthreads();

    int r = t >> 5, c0 = (t & 31)*4;
    {
        float4 a0 = *(const float4*)&ob1[c0];
        float4 a1 = make_float4(0,0,0,0);
        #pragma unroll 8
        for (int i = 0; i < INVD; i += 2) {
            float x0v = inS[r][i], x1v = inS[r][i+1];
            float4 w0 = *(const float4*)&ow1[i*HID + c0];
            float4 w1 = *(const float4*)&ow1[(i+1)*HID + c0];
            a0.x += x0v*w0.x; a0.y += x0v*w0.y; a0.z += x0v*w0.z; a0.w += x0v*w0.w;
            a1.x += x1v*w1.x; a1.y += x1v*w1.y; a1.z += x1v*w1.z; a1.w += x1v*w1.w;
        }
        l1S[r][c0]   = silu_f(a0.x + a1.x); l1S[r][c0+1] = silu_f(a0.y + a1.y);
        l1S[r][c0+2] = silu_f(a0.z + a1.z); l1S[r][c0+3] = silu_f(a0.w + a1.w);
    }
    __syncthreads();
    {
        float4 a0 = *(const float4*)&ob2[c0];
        float4 a1 = make_float4(0,0,0,0);
        #pragma unroll 8
        for (int i = 0; i < HID; i += 2) {
            float x0v = l1S[r][i], x1v = l1S[r][i+1];
            float4 w0 = *(const float4*)&ow2[i*HID + c0];
            float4 w1 = *(const float4*)&ow2[(i+1)*HID + c0];
            a0.x += x0v*w0.x; a0.y += x0v*w0.y; a0.z += x0v*w0.z; a0.w += x0v*w0.w;
            a1.x += x1v*w1.x; a1.y += x1v*w1.y; a1.z += x1v*w1.z; a1.w += x1v*w1.w;
        }
        l2S[r][c0]   = silu_f(a0.x + a1.x); l2S[r][c0+1] = silu_f(a0.y + a1.y);
        l2S[r][c0+2] = silu_f(a0.z + a1.z); l2S[r][c0+3] = silu_f(a0.w + a1.w);
    }
    __syncthreads();
    {
        float4 a0 = *(const float4*)&ob3[c0];
        float4 a1 = make_float4(0,0,0,0);
        #pragma unroll 8
        for (int i = 0; i < HID; i += 2) {
            float x0v = l2S[r][i], x1v = l2S[r][i+1];
            float4 w0 = *(const float4*)&ow3[i*HID + c0];
            float4 w1 = *(const float4*)&ow3[(i+1)*HID + c0];
            a0.x += x0v*w0.x; a0.y += x0v*w0.y; a0.z += x0v*w0.z; a0.w += x0v*w0.w;
            a1.x += x1v*w1.x; a1.y += x1v*w1.y; a1.z += x1v*w1.z; a1.w += x1v*w1.w;
        }
        float4 o;
        o.x = a0.x + a1.x; o.y = a0.y + a1.y; o.z = a0.z + a1.z; o.w = a0.w + a1.w;
        *(float4*)&out[((b*NE + e0) + r)*LAT + c0] = o;
    }
}

extern "C" void kernel_launch(void* const* d_in, const int* in_sizes, int n_in,
                              void* d_out, int out_size, void* d_ws, size_t ws_size,
                              hipStream_t stream) {
    const float* h        = (const float*)d_in[0];
    const float* h_full   = (const float*)d_in[1];
    const float* e_feat   = (const float*)d_in[2];
    const float* att_dist = (const float*)d_in[3];
    const float* att_vec  = (const float*)d_in[4];
    const float* z_emb    = (const float*)d_in[5];
    const float* rw1 = (const float*)d_in[6];  const float* rb1 = (const float*)d_in[7];
    const float* rw2 = (const float*)d_in[8];  const float* rb2 = (const float*)d_in[9];
    const float* ew1 = (const float*)d_in[10]; const float* eb1 = (const float*)d_in[11];
    const float* ew2 = (const float*)d_in[12]; const float* eb2 = (const float*)d_in[13];
    const float* qw1 = (const float*)d_in[14]; const float* qb1 = (const float*)d_in[15];
    const float* qw2 = (const float*)d_in[16]; const float* qb2 = (const float*)d_in[17];
    const float* qw3 = (const float*)d_in[18]; const float* qb3 = (const float*)d_in[19];
    const float* kw1 = (const float*)d_in[20]; const float* kb1 = (const float*)d_in[21];
    const float* kw2 = (const float*)d_in[22]; const float* kb2 = (const float*)d_in[23];
    const float* kw3 = (const float*)d_in[24]; const float* kb3 = (const float*)d_in[25];
    const float* ow1 = (const float*)d_in[26]; const float* ob1 = (const float*)d_in[27];
    const float* ow2 = (const float*)d_in[28]; const float* ob2 = (const float*)d_in[29];
    const float* ow3 = (const float*)d_in[30]; const float* ob3 = (const float*)d_in[31];
    const int* z        = (const int*)d_in[32];
    const int* absorber = (const int*)d_in[34];
    const int* att_dst  = (const int*)d_in[35];

    float* ws = (float*)d_ws;
    int*   inv     = (int*)ws;                    // 1536
    float* y1E     = ws + 1536;                   // 3072
    float* envE    = ws + 4608;                   // 1024
    float* kmat    = ws + 5632;                   // 196608 (1536x128)
    float* qmat    = ws + 202240;                 // 524288 (4096x128)
    float* gexp    = ws + 726528;                 // 20480
    float* virr    = ws + 747008;                 // 122880 (1536x80)
    float* habs1   = ws + 869888;                 // 2048
    float* ec      = ws + 871936;                 // 32768
    float* scoresW = ws + 904704;                 // 393216 (4096x96)
    __half* tpwE   = (__half*)(ws + 1297920);     // 4718592 halves
    __half* rw2T   = (__half*)(ws + 3657216);     // 589824 halves (4608x128)
    __half* hiddenH= (__half*)(ws + 3952128);     // 131072 halves (1024x128)

    float* out = (float*)d_out;

    k_stage1<<<STAGE1_BLKS, 256, 0, stream>>>(h, z_emb, z, absorber, e_feat,
                                              att_dst, att_dist, att_vec,
                                              rw1, rb1, kw1, kb1, kw2, kb2, kw3, kb3,
                                              qw1, ew1, eb1, ew2, eb2, rw2,
                                              hiddenH, kmat, ec, habs1, gexp, rw2T,
                                              inv, y1E, envE);
    k_mq<<<MQ_BLKS, 256, 0, stream>>>(hiddenH, rw2T, rb2, habs1, ec, qb1,
                                      qw2, qb2, qw3, qb3, tpwE, qmat);
    k_st<<<ST_BLKS, 256, 0, stream>>>(qmat, kmat, inv, h_full, tpwE, att_dst,
                                      envE, y1E, scoresW, virr);
    k_attf<<<BB*32, 256, 0, stream>>>(scoresW, inv, virr, gexp,
                                      ow1, ob1, ow2, ob2, ow3, ob3, out);
}